// Round 1
// baseline (454.666 us; speedup 1.0000x reference)
//
#include <hip/hip_runtime.h>
#include <hip/hip_bf16.h>
#include <math.h>

// Problem constants: x [8, 96, 256, 256] fp32, window 16x16 -> 2048 windows.
#define NWIN 2048

typedef __bf16 v8bf __attribute__((ext_vector_type(8)));
typedef __bf16 v2bf __attribute__((ext_vector_type(2)));
typedef float  v4f  __attribute__((ext_vector_type(4)));
typedef unsigned int v4u __attribute__((ext_vector_type(4)));

// Kernel 1: per-window alpha = 1 + sigmoid(SE(pool(real_conv))) where
// pool(real_conv)[o] = sum_c Wr[o,c] * x_win[c,0,0]/16 + b_r[o].
// Block 2048 computes the global beta vector from b_imag.
__global__ __launch_bounds__(128) void se_alpha_kernel(
    const float* __restrict__ x,
    const float* __restrict__ w_real, const float* __restrict__ b_real,
    const float* __restrict__ car_w1, const float* __restrict__ car_b1,
    const float* __restrict__ car_w2, const float* __restrict__ car_b2,
    const float* __restrict__ b_imag,
    const float* __restrict__ cai_w1, const float* __restrict__ cai_b1,
    const float* __restrict__ cai_w2, const float* __restrict__ cai_b2,
    float* __restrict__ alpha, float* __restrict__ beta)
{
    __shared__ float wr_s[96 * 97];   // +1 pad: lane-varying row -> 2-way banks
    __shared__ float vec_s[96];
    __shared__ float pr_s[96];
    __shared__ float h1_s[32];
    const int t = threadIdx.x;
    const int n = blockIdx.x;

    if (n < NWIN) {
        const int b = n >> 8, wh = (n >> 4) & 15, ww = n & 15;
        for (int idx = t; idx < 96 * 96; idx += 128) {
            int o = idx / 96;
            int c = idx - o * 96;
            wr_s[o * 97 + c] = w_real[idx];
        }
        if (t < 96)
            vec_s[t] = x[(((size_t)(b * 96 + t)) * 256 + wh * 16) * 256 + ww * 16];
        __syncthreads();
        if (t < 96) {
            float acc = 0.f;
            #pragma unroll 8
            for (int c = 0; c < 96; ++c) acc += wr_s[t * 97 + c] * vec_s[c];
            pr_s[t] = acc * (1.0f / 16.0f) + b_real[t];
        }
        __syncthreads();
        if (t < 32) {
            float acc = car_b1[t];
            for (int o = 0; o < 96; ++o) acc += car_w1[t * 96 + o] * pr_s[o];
            h1_s[t] = fmaxf(acc, 0.f);
        }
        __syncthreads();
        if (t < 96) {
            float acc = car_b2[t];
            for (int j = 0; j < 32; ++j) acc += car_w2[t * 32 + j] * h1_s[j];
            alpha[n * 96 + t] = 1.f + 1.f / (1.f + __expf(-acc));
        }
    } else {
        // beta: pooled imag part is exactly b_imag (mean of Im(fft) of real x = 0)
        if (t < 32) {
            float acc = cai_b1[t];
            for (int o = 0; o < 96; ++o) acc += cai_w1[t * 96 + o] * b_imag[o];
            h1_s[t] = fmaxf(acc, 0.f);
        }
        __syncthreads();
        if (t < 96) {
            float acc = cai_b2[t];
            for (int j = 0; j < 32; ++j) acc += cai_w2[t * 32 + j] * h1_s[j];
            beta[t] = 1.f + 1.f / (1.f + __expf(-acc));
        }
    }
}

// Kernel 2 (restructured): per window
//   out[p,o] = alpha[n,o]*U[p,o] + V[p,o]  (+ 16*alpha*b_r at p=(0,0))
//   U = (Wr/2) * (x_p + x_flip(p)),  V = (beta.*Wi/2) * (x_p - x_flip(p))
// Weights are WINDOW-INDEPENDENT -> staged once per block (bf16, pre-scaled);
// each block sweeps 8 windows with double-buffered x staging (issue-early /
// write-late) so HBM loads stay in flight across the compute phase.
// 1024 threads = 16 waves; wave wv owns pixel row h=wv (one 16-wide m-tile).
// acc = U[6]+V[6] v4f = 48 VGPR -> <=128 VGPR -> all 16 waves resident.
// LDS: 2 x 96x104 bf16 weights (row 208B: 16B-aligned, 20-bank stride)
//    + 2 x 256x40 bf16 x-buffers (same layout as previous version) = 80,896 B.
__global__ __launch_bounds__(1024, 4) void wfca_main_kernel(
    const float* __restrict__ x,
    const float* __restrict__ w_real, const float* __restrict__ w_imag,
    const float* __restrict__ b_real,
    const float* __restrict__ alpha, const float* __restrict__ beta,
    float* __restrict__ out)
{
    __shared__ __bf16 wr_s[96 * 104];        // 0.5*Wr
    __shared__ __bf16 wi_s[96 * 104];        // 0.5*beta[o]*Wi
    __shared__ __bf16 x_lds[2][256 * 40];    // [pixel][chan-in-chunk], dbuf

    const int t    = threadIdx.x;
    const int blk  = blockIdx.x;             // 256 blocks, 8 windows each
    const int b    = blk >> 5;               // batch
    const int wh   = (blk >> 1) & 15;        // window row
    const int ww0  = (blk & 1) * 8;          // first window col

    const int lane = t & 63;
    const int l16  = lane & 15;
    const int quad = lane >> 4;
    const int wv   = t >> 6;                 // wave id = pixel row h (0..15)

    // staging decomposition: (w-pixel fast -> conflict-free LDS writes)
    const int sw  = t & 15;                  // w coordinate
    const int scp = (t >> 4) & 15;           // channel pair 0..15
    const int hq  = t >> 8;                  // 0..3 -> rows hq*4..hq*4+3

    const float* xb = x + (((size_t)(b * 96)) << 16) + (size_t)(wh * 16) * 256;

    float st0[4], st1[4];                    // staged regs (next phase's data)

    auto stage_issue = [&](int win_, int k_) {
        const float* xp = xb + (((size_t)(k_ * 32 + 2 * scp)) << 16)
                             + (ww0 + win_) * 16 + sw;
        #pragma unroll
        for (int r = 0; r < 4; ++r) {
            int h = hq * 4 + r;
            st0[r] = xp[h * 256];
            st1[r] = xp[h * 256 + 65536];
        }
    };
    auto stage_write = [&](int bufsel) {
        #pragma unroll
        for (int r = 0; r < 4; ++r) {
            int h = hq * 4 + r;
            v2bf pk;
            pk[0] = (__bf16)st0[r];
            pk[1] = (__bf16)st1[r];
            *(v2bf*)&x_lds[bufsel][(h * 16 + sw) * 40 + 2 * scp] = pk;
        }
    };

    // ---- prologue: issue win0/chunk0 x loads + stage weights once ----
    stage_issue(0, 0);
    float wrv[9], wiv[9], btv[9];
    #pragma unroll
    for (int r = 0; r < 9; ++r) {
        int idx = t + r * 1024;              // 9*1024 = 9216 = 96*96 exact
        wrv[r] = w_real[idx];
        wiv[r] = w_imag[idx];
        btv[r] = beta[idx / 96];
    }
    float brv[6];
    #pragma unroll
    for (int n = 0; n < 6; ++n) brv[n] = b_real[n * 16 + l16];
    #pragma unroll
    for (int r = 0; r < 9; ++r) {
        int idx = t + r * 1024;
        int o = idx / 96, c = idx - o * 96;
        wr_s[o * 104 + c] = (__bf16)(0.5f * wrv[r]);
        wi_s[o * 104 + c] = (__bf16)(0.5f * btv[r] * wiv[r]);
    }
    stage_write(0);
    __syncthreads();

    v4f U[6], V[6];
    int cur = 0;
    for (int win = 0; win < 8; ++win) {
        float af[6];
        #pragma unroll
        for (int n = 0; n < 6; ++n) {
            af[n] = alpha[(size_t)(blk * 8 + win) * 96 + n * 16 + l16];
            U[n] = v4f{0.f, 0.f, 0.f, 0.f};
            V[n] = v4f{0.f, 0.f, 0.f, 0.f};
        }
        for (int k = 0; k < 3; ++k) {
            const bool last = (win == 7 && k == 2);
            // issue next phase's global loads BEFORE compute (latency overlap)
            if (!last) stage_issue(k == 2 ? win + 1 : win, k == 2 ? 0 : k + 1);

            const __bf16* xl = x_lds[cur];
            // A frags: m-index = l16 = pixel w within row wv
            v8bf a_x = *(const v8bf*)&xl[(wv * 16 + l16) * 40 + quad * 8];
            const int hf = (16 - wv) & 15, wf = (16 - l16) & 15;
            v8bf a_f = *(const v8bf*)&xl[(hf * 16 + wf) * 40 + quad * 8];
            // exact bf16 negation of flipped fragment (sign-bit XOR)
            v4u fu = __builtin_bit_cast(v4u, a_f);
            const v4u sm = {0x80008000u, 0x80008000u, 0x80008000u, 0x80008000u};
            v8bf a_fn = __builtin_bit_cast(v8bf, fu ^ sm);

            const int c0 = k * 32;
            #pragma unroll
            for (int n = 0; n < 6; ++n) {
                v8bf bwr = *(const v8bf*)&wr_s[(n * 16 + l16) * 104 + c0 + quad * 8];
                v8bf bwi = *(const v8bf*)&wi_s[(n * 16 + l16) * 104 + c0 + quad * 8];
                U[n] = __builtin_amdgcn_mfma_f32_16x16x32_bf16(a_x,  bwr, U[n], 0, 0, 0);
                U[n] = __builtin_amdgcn_mfma_f32_16x16x32_bf16(a_f,  bwr, U[n], 0, 0, 0);
                V[n] = __builtin_amdgcn_mfma_f32_16x16x32_bf16(a_x,  bwi, V[n], 0, 0, 0);
                V[n] = __builtin_amdgcn_mfma_f32_16x16x32_bf16(a_fn, bwi, V[n], 0, 0, 0);
            }
            if (k == 2) {
                // epilogue: C/D layout col=l16 (out-ch), row=quad*4+r (= w)
                const int col = (ww0 + win) * 16;
                #pragma unroll
                for (int n = 0; n < 6; ++n) {
                    const int o = n * 16 + l16;
                    v4f v;
                    #pragma unroll
                    for (int r = 0; r < 4; ++r) v[r] = af[n] * U[n][r] + V[n][r];
                    if (wv == 0 && quad == 0) v[0] += 16.f * af[n] * brv[n];
                    size_t idx = (((size_t)(b * 96 + o)) * 256 + wh * 16 + wv) * 256
                                 + col + quad * 4;
                    *(v4f*)(out + idx) = v;
                }
            }
            // write-late: staged regs -> other buffer (compiler waits vmcnt here)
            if (!last) stage_write(cur ^ 1);
            __syncthreads();
            cur ^= 1;
        }
    }
}

extern "C" void kernel_launch(void* const* d_in, const int* in_sizes, int n_in,
                              void* d_out, int out_size, void* d_ws, size_t ws_size,
                              hipStream_t stream) {
    const float* x      = (const float*)d_in[0];
    const float* w_real = (const float*)d_in[1];
    const float* b_real = (const float*)d_in[2];
    const float* w_imag = (const float*)d_in[3];
    const float* b_imag = (const float*)d_in[4];
    const float* car_w1 = (const float*)d_in[5];
    const float* car_b1 = (const float*)d_in[6];
    const float* car_w2 = (const float*)d_in[7];
    const float* car_b2 = (const float*)d_in[8];
    const float* cai_w1 = (const float*)d_in[9];
    const float* cai_b1 = (const float*)d_in[10];
    const float* cai_w2 = (const float*)d_in[11];
    const float* cai_b2 = (const float*)d_in[12];
    float* out = (float*)d_out;

    float* alpha = (float*)d_ws;            // [2048*96]
    float* beta  = alpha + NWIN * 96;       // [96]

    se_alpha_kernel<<<NWIN + 1, 128, 0, stream>>>(
        x, w_real, b_real, car_w1, car_b1, car_w2, car_b2,
        b_imag, cai_w1, cai_b1, cai_w2, cai_b2, alpha, beta);

    wfca_main_kernel<<<256, 1024, 0, stream>>>(
        x, w_real, w_imag, b_real, alpha, beta, out);
}

// Round 2
// 441.533 us; speedup vs baseline: 1.0297x; 1.0297x over previous
//
#include <hip/hip_runtime.h>
#include <hip/hip_bf16.h>
#include <math.h>

// Problem constants: x [8, 96, 256, 256] fp32, window 16x16 -> 2048 windows.
#define NWIN 2048

typedef __bf16 v8bf __attribute__((ext_vector_type(8)));
typedef __bf16 v2bf __attribute__((ext_vector_type(2)));
typedef float  v4f  __attribute__((ext_vector_type(4)));
typedef unsigned int v4u __attribute__((ext_vector_type(4)));

// Kernel 1: per-window alpha = 1 + sigmoid(SE(pool(real_conv))) where
// pool(real_conv)[o] = sum_c Wr[o,c] * x_win[c,0,0]/16 + b_r[o].
// Block 2048 computes the global beta vector from b_imag.
__global__ __launch_bounds__(128) void se_alpha_kernel(
    const float* __restrict__ x,
    const float* __restrict__ w_real, const float* __restrict__ b_real,
    const float* __restrict__ car_w1, const float* __restrict__ car_b1,
    const float* __restrict__ car_w2, const float* __restrict__ car_b2,
    const float* __restrict__ b_imag,
    const float* __restrict__ cai_w1, const float* __restrict__ cai_b1,
    const float* __restrict__ cai_w2, const float* __restrict__ cai_b2,
    float* __restrict__ alpha, float* __restrict__ beta)
{
    __shared__ float wr_s[96 * 97];   // +1 pad: lane-varying row -> 2-way banks
    __shared__ float vec_s[96];
    __shared__ float pr_s[96];
    __shared__ float h1_s[32];
    const int t = threadIdx.x;
    const int n = blockIdx.x;

    if (n < NWIN) {
        const int b = n >> 8, wh = (n >> 4) & 15, ww = n & 15;
        for (int idx = t; idx < 96 * 96; idx += 128) {
            int o = idx / 96;
            int c = idx - o * 96;
            wr_s[o * 97 + c] = w_real[idx];
        }
        if (t < 96)
            vec_s[t] = x[(((size_t)(b * 96 + t)) * 256 + wh * 16) * 256 + ww * 16];
        __syncthreads();
        if (t < 96) {
            float acc = 0.f;
            #pragma unroll 8
            for (int c = 0; c < 96; ++c) acc += wr_s[t * 97 + c] * vec_s[c];
            pr_s[t] = acc * (1.0f / 16.0f) + b_real[t];
        }
        __syncthreads();
        if (t < 32) {
            float acc = car_b1[t];
            for (int o = 0; o < 96; ++o) acc += car_w1[t * 96 + o] * pr_s[o];
            h1_s[t] = fmaxf(acc, 0.f);
        }
        __syncthreads();
        if (t < 96) {
            float acc = car_b2[t];
            for (int j = 0; j < 32; ++j) acc += car_w2[t * 32 + j] * h1_s[j];
            alpha[n * 96 + t] = 1.f + 1.f / (1.f + __expf(-acc));
        }
    } else {
        // beta: pooled imag part is exactly b_imag (mean of Im(fft) of real x = 0)
        if (t < 32) {
            float acc = cai_b1[t];
            for (int o = 0; o < 96; ++o) acc += cai_w1[t * 96 + o] * b_imag[o];
            h1_s[t] = fmaxf(acc, 0.f);
        }
        __syncthreads();
        if (t < 96) {
            float acc = cai_b2[t];
            for (int j = 0; j < 32; ++j) acc += cai_w2[t * 32 + j] * h1_s[j];
            beta[t] = 1.f + 1.f / (1.f + __expf(-acc));
        }
    }
}

// Kernel 2: per window n:
//   out[p,o] = alpha[n,o]*U[p,o] + V[p,o]  (+ 16*alpha*b_r at p=(0,0))
//   U = (Wr/2)*(x_p + x_flip(p)),  V = (beta.*Wi/2)*(x_p - x_flip(p))
// alpha is constant over K, so it is folded PER K-CHUNK via VALU FMA:
//   utmp = mfma(Wr-part, C=0);  acc = mfma(Wi-part, acc);  acc += alpha*utmp
// -> only acc[6] (24 regs) persists; total reg demand ~80 << 128 budget,
//    no spills (round-1 regression: 48-reg U/V acc forced spills at the
//    launch_bounds(1024,4) 128-reg cap -> +78MB scratch traffic).
// Weights window-independent -> staged once per block; 8 windows/block with
// double-buffered x staging (issue-early / write-late).
__global__ __launch_bounds__(1024, 4) void wfca_main_kernel(
    const float* __restrict__ x,
    const float* __restrict__ w_real, const float* __restrict__ w_imag,
    const float* __restrict__ b_real,
    const float* __restrict__ alpha, const float* __restrict__ beta,
    float* __restrict__ out)
{
    __shared__ __bf16 wr_s[96 * 104];        // 0.5*Wr
    __shared__ __bf16 wi_s[96 * 104];        // 0.5*beta[o]*Wi
    __shared__ __bf16 x_lds[2][256 * 40];    // [pixel][chan-in-chunk], dbuf

    const int t    = threadIdx.x;
    const int blk  = blockIdx.x;             // 256 blocks, 8 windows each
    const int b    = blk >> 5;               // batch
    const int wh   = (blk >> 1) & 15;        // window row
    const int ww0  = (blk & 1) * 8;          // first window col

    const int lane = t & 63;
    const int l16  = lane & 15;
    const int quad = lane >> 4;
    const int wv   = t >> 6;                 // wave id = pixel row h (0..15)

    // staging decomposition: (w-pixel fast -> conflict-free LDS writes)
    const int sw  = t & 15;                  // w coordinate
    const int scp = (t >> 4) & 15;           // channel pair 0..15
    const int hq  = t >> 8;                  // 0..3 -> rows hq*4..hq*4+3

    const float* xb = x + (((size_t)(b * 96)) << 16) + (size_t)(wh * 16) * 256;

    float st0[4], st1[4];                    // staged regs (next phase's data)

    auto stage_issue = [&](int win_, int k_) {
        const float* xp = xb + (((size_t)(k_ * 32 + 2 * scp)) << 16)
                             + (ww0 + win_) * 16 + sw;
        #pragma unroll
        for (int r = 0; r < 4; ++r) {
            int h = hq * 4 + r;
            st0[r] = xp[h * 256];
            st1[r] = xp[h * 256 + 65536];
        }
    };
    auto stage_write = [&](int bufsel) {
        #pragma unroll
        for (int r = 0; r < 4; ++r) {
            int h = hq * 4 + r;
            v2bf pk;
            pk[0] = (__bf16)st0[r];
            pk[1] = (__bf16)st1[r];
            *(v2bf*)&x_lds[bufsel][(h * 16 + sw) * 40 + 2 * scp] = pk;
        }
    };

    // ---- prologue: issue win0/chunk0 x loads + stage weights once ----
    stage_issue(0, 0);
    {
        float wrv[9], wiv[9], btv[9];
        #pragma unroll
        for (int r = 0; r < 9; ++r) {
            int idx = t + r * 1024;          // 9*1024 = 9216 = 96*96 exact
            wrv[r] = w_real[idx];
            wiv[r] = w_imag[idx];
            btv[r] = beta[idx / 96];
        }
        #pragma unroll
        for (int r = 0; r < 9; ++r) {
            int idx = t + r * 1024;
            int o = idx / 96, c = idx - o * 96;
            wr_s[o * 104 + c] = (__bf16)(0.5f * wrv[r]);
            wi_s[o * 104 + c] = (__bf16)(0.5f * btv[r] * wiv[r]);
        }
    }
    stage_write(0);
    __syncthreads();

    v4f acc[6];
    int cur = 0;
    for (int win = 0; win < 8; ++win) {
        float af[6];
        #pragma unroll
        for (int n = 0; n < 6; ++n) {
            af[n] = alpha[(size_t)(blk * 8 + win) * 96 + n * 16 + l16];
            acc[n] = v4f{0.f, 0.f, 0.f, 0.f};
        }
        for (int k = 0; k < 3; ++k) {
            const bool last = (win == 7 && k == 2);
            // issue next phase's global loads BEFORE compute (latency overlap)
            if (!last) stage_issue(k == 2 ? win + 1 : win, k == 2 ? 0 : k + 1);

            const __bf16* xl = x_lds[cur];
            // A frags: m-index = l16 = pixel w within row wv
            v8bf a_x = *(const v8bf*)&xl[(wv * 16 + l16) * 40 + quad * 8];
            const int hf = (16 - wv) & 15, wf = (16 - l16) & 15;
            v8bf a_f = *(const v8bf*)&xl[(hf * 16 + wf) * 40 + quad * 8];
            // exact bf16 negation of flipped fragment (sign-bit XOR)
            v4u fu = __builtin_bit_cast(v4u, a_f);
            const v4u sm = {0x80008000u, 0x80008000u, 0x80008000u, 0x80008000u};
            v8bf a_fn = __builtin_bit_cast(v8bf, fu ^ sm);

            const int c0 = k * 32;
            #pragma unroll
            for (int n = 0; n < 6; ++n) {
                v8bf bwr = *(const v8bf*)&wr_s[(n * 16 + l16) * 104 + c0 + quad * 8];
                v8bf bwi = *(const v8bf*)&wi_s[(n * 16 + l16) * 104 + c0 + quad * 8];
                // Wi part accumulates straight into acc
                acc[n] = __builtin_amdgcn_mfma_f32_16x16x32_bf16(a_x,  bwi, acc[n], 0, 0, 0);
                acc[n] = __builtin_amdgcn_mfma_f32_16x16x32_bf16(a_fn, bwi, acc[n], 0, 0, 0);
                // Wr part into a transient, then alpha-scaled VALU FMA
                v4f utmp = __builtin_amdgcn_mfma_f32_16x16x32_bf16(
                               a_x, bwr, v4f{0.f, 0.f, 0.f, 0.f}, 0, 0, 0);
                utmp = __builtin_amdgcn_mfma_f32_16x16x32_bf16(a_f, bwr, utmp, 0, 0, 0);
                #pragma unroll
                for (int r = 0; r < 4; ++r) acc[n][r] += af[n] * utmp[r];
            }
            if (k == 2) {
                // epilogue: C/D layout col=l16 (out-ch), row=quad*4+r (= w)
                const int col = (ww0 + win) * 16;
                #pragma unroll
                for (int n = 0; n < 6; ++n) {
                    const int o = n * 16 + l16;
                    v4f v = acc[n];
                    if (wv == 0 && quad == 0) {
                        // bias delta at (0,0): IFFT of const b_r over bins = 16*b_r
                        v[0] += 16.f * af[n] * b_real[o];
                    }
                    size_t idx = (((size_t)(b * 96 + o)) * 256 + wh * 16 + wv) * 256
                                 + col + quad * 4;
                    *(v4f*)(out + idx) = v;
                }
            }
            // write-late: staged regs -> other buffer (compiler waits vmcnt here)
            if (!last) stage_write(cur ^ 1);
            __syncthreads();
            cur ^= 1;
        }
    }
}

extern "C" void kernel_launch(void* const* d_in, const int* in_sizes, int n_in,
                              void* d_out, int out_size, void* d_ws, size_t ws_size,
                              hipStream_t stream) {
    const float* x      = (const float*)d_in[0];
    const float* w_real = (const float*)d_in[1];
    const float* b_real = (const float*)d_in[2];
    const float* w_imag = (const float*)d_in[3];
    const float* b_imag = (const float*)d_in[4];
    const float* car_w1 = (const float*)d_in[5];
    const float* car_b1 = (const float*)d_in[6];
    const float* car_w2 = (const float*)d_in[7];
    const float* car_b2 = (const float*)d_in[8];
    const float* cai_w1 = (const float*)d_in[9];
    const float* cai_b1 = (const float*)d_in[10];
    const float* cai_w2 = (const float*)d_in[11];
    const float* cai_b2 = (const float*)d_in[12];
    float* out = (float*)d_out;

    float* alpha = (float*)d_ws;            // [2048*96]
    float* beta  = alpha + NWIN * 96;       // [96]

    se_alpha_kernel<<<NWIN + 1, 128, 0, stream>>>(
        x, w_real, b_real, car_w1, car_b1, car_w2, car_b2,
        b_imag, cai_w1, cai_b1, cai_w2, cai_b2, alpha, beta);

    wfca_main_kernel<<<256, 1024, 0, stream>>>(
        x, w_real, w_imag, b_real, alpha, beta, out);
}